// Round 2
// baseline (4248.107 us; speedup 1.0000x reference)
//
#include <hip/hip_runtime.h>

#define SWEEPS 6
#define HSTRIDE 4112   // hTbuf row stride: 4096 + front pad(1) + slack, %4==0
#define WROW 140       // skewed W image row: pc(rl) = rl + 4*(rl>>5), max 139
#define WTSZ (8 * 256 * WROW)   // one W image: 8 rtiles x 256 k x 140
#define SMEMF 13056    // union LDS (floats): w 2*4480 + h 2*2048 = 52224 B
#define NBLK 512u      // fused grid size; 2 blocks/CU x 256 CU, all co-resident

__device__ __forceinline__ float sig_(float x) { return 1.0f / (1.0f + __expf(-x)); }
__device__ __forceinline__ float th_(float x)  { return 1.0f - 2.0f / (__expf(2.0f * x) + 1.0f); }

// async global->LDS, 16B per lane. LDS dest rule: wave-uniform base + lane*16.
__device__ __forceinline__ void gload_lds16(const float* g, float* l) {
    __builtin_amdgcn_global_load_lds(
        (const __attribute__((address_space(1))) unsigned*)g,
        (__attribute__((address_space(3))) unsigned*)l, 16, 0, 0);
}

// ---------------------------------------------------------------------------
// Hand-rolled grid barrier (no cooperative launch needed). Correct under
// XCD non-coherence: __threadfence() release (buffer_wbl2) before arrival,
// acquire (buffer_inv) after release observed. bar[0]=count, bar[1]=gen;
// zeroed by setup_k each launch (workspace is re-poisoned between iters).
// All NBLK blocks are co-resident by construction (see launch_bounds math).
// ---------------------------------------------------------------------------
__device__ __forceinline__ void gbar(unsigned* bar, unsigned nblk) {
    __threadfence();                       // release: flush this thread's writes
    __syncthreads();
    if (threadIdx.x == 0) {
        unsigned g = __hip_atomic_load(&bar[1], __ATOMIC_RELAXED,
                                       __HIP_MEMORY_SCOPE_AGENT);
        unsigned a = __hip_atomic_fetch_add(&bar[0], 1u, __ATOMIC_ACQ_REL,
                                            __HIP_MEMORY_SCOPE_AGENT);
        if (a == nblk - 1u) {
            __hip_atomic_store(&bar[0], 0u, __ATOMIC_RELAXED,
                               __HIP_MEMORY_SCOPE_AGENT);
            __hip_atomic_store(&bar[1], g + 1u, __ATOMIC_RELEASE,
                               __HIP_MEMORY_SCOPE_AGENT);
        } else {
            // relaxed poll (no per-poll cache inv); acquire fence after exit
            while (__hip_atomic_load(&bar[1], __ATOMIC_RELAXED,
                                     __HIP_MEMORY_SCOPE_AGENT) == g)
                __builtin_amdgcn_s_sleep(2);
        }
    }
    __syncthreads();
    __threadfence();                       // acquire: invalidate L1/L2 before reads
}

// ===========================================================================
// setup_k: blocks 0..191 = three wtrans images (64 blocks each),
//          block 192 = counting sort by length (desc) + hTbuf col0 zero
//          + grid-barrier state init.
// ===========================================================================
__global__ __launch_bounds__(256)
void setup_k(const float* __restrict__ tWhh, const float* __restrict__ iWhh,
             const float* __restrict__ iWih, float* __restrict__ tWhhT,
             float* __restrict__ iWhhT, float* __restrict__ iWihT,
             const int* __restrict__ len, int* __restrict__ perm,
             int* __restrict__ actcnt, float* __restrict__ hTbuf,
             unsigned* __restrict__ bar)
{
    __shared__ __align__(16) float s[32 * WROW];
    __shared__ int cnt[17], off[17];
    const int tid = threadIdx.x;
    const int b = blockIdx.x;
    if (b < 192) {
        // WT[rt][k][pc(rl)] = W[rowmap(rt,rl)][k]; ilv=1: gate-interleaved
        const float* W; float* WT; int ilv;
        if (b < 64)       { W = tWhh; WT = tWhhT; ilv = 1; }
        else if (b < 128) { W = iWhh; WT = iWhhT; ilv = 0; }
        else              { W = iWih; WT = iWihT; ilv = 0; }
        const int bb = b & 63;
        const int k0 = (bb & 7) * 32;
        const int rt = bb >> 3;
        #pragma unroll
        for (int p = 0; p < 4; ++p) {
            int idx = tid + p * 256;
            int rl = idx >> 3, k4 = idx & 7;
            int row = ilv ? ((rl & 3) * 256 + rt * 32 + (rl >> 2))
                          : (rt * 128 + rl);
            float4 v = *(const float4*)&W[row * 256 + k0 + k4 * 4];
            int pc = rl + ((rl >> 5) << 2);
            s[(k4 * 4 + 0) * WROW + pc] = v.x;
            s[(k4 * 4 + 1) * WROW + pc] = v.y;
            s[(k4 * 4 + 2) * WROW + pc] = v.z;
            s[(k4 * 4 + 3) * WROW + pc] = v.w;
        }
        __syncthreads();
        float* dst = WT + (size_t)(rt * 256 + k0) * WROW;
        for (int i = tid; i < 32 * WROW; i += 256) dst[i] = s[i];
    } else {
        if (tid < 17) cnt[tid] = 0;
        __syncthreads();
        for (int n = tid; n < 4096; n += 256) atomicAdd(&cnt[len[n]], 1);
        __syncthreads();
        if (tid == 0) {
            int run = 0;
            for (int L = 16; L >= 1; --L) { off[L] = run; run += cnt[L]; }
            actcnt[16] = 0;
            for (int t = 1; t < 16; ++t) actcnt[t] = off[t];
            actcnt[0] = 4096;
            bar[0] = 0u;                  // grid-barrier count
            bar[1] = 0u;                  // grid-barrier generation
        }
        __syncthreads();
        for (int n = tid; n < 4096; n += 256) {
            int pos = atomicAdd(&off[len[n]], 1);
            perm[pos] = n;
        }
        hTbuf[tid * HSTRIDE] = 0.f;       // h[-1] = 0 (only col 0 is ever read)
    }
}

// ===========================================================================
// Shared 128r x 64s GEMM body (validated r9 pattern, bit-identical inner
// loop): skewed W image + h both staged via linear async global_load_lds,
// double-buffered, 1 barrier/chunk. acc[ri][si] += W[r][k]*X[k][s].
// ===========================================================================
__device__ __forceinline__ void gemm128x64_body(
    int tid, float* smem, const float* __restrict__ WT, int rt,
    const float* __restrict__ X, int xstride, int s0, float acc[8][4])
{
    float* wl = smem;            // [2][32*WROW]
    float* hl = smem + 8960;     // [2][32][64]
    const int tr = tid & 15;
    const int ts = tid >> 4;
    const int wphys = tr * 8 + ((tr >> 2) << 2);

    auto issue_w = [&](int c, int b) {    // 1120 16B units, linear stream
        const float* src = WT + (size_t)(rt * 256 + c * 32) * WROW;
        float* dstb = wl + b * 4480;
        #pragma unroll
        for (int p = 0; p < 4; ++p) {
            int idx = tid + p * 256;
            gload_lds16(src + idx * 4, dstb + idx * 4);
        }
        if (tid < 96) {
            int idx = 1024 + tid;
            gload_lds16(src + idx * 4, dstb + idx * 4);
        }
    };
    auto issue_h = [&](int k0, int b) {
        float* dstb = hl + b * 2048;
        #pragma unroll
        for (int p = 0; p < 2; ++p) {
            int idx = tid + p * 256;
            int jj = idx >> 4, s4 = idx & 15;
            gload_lds16(&X[(size_t)(k0 + jj) * xstride + s0 + s4 * 4],
                        dstb + jj * 64 + s4 * 4);
        }
    };

    issue_w(0, 0); issue_h(0, 0); __syncthreads();
    for (int c = 0; c < 8; ++c) {
        const int b = c & 1;
        if (c < 7) { issue_w(c + 1, b ^ 1); issue_h((c + 1) * 32, b ^ 1); }
        const float* wb = wl + b * 4480;
        const float* hb = hl + b * 2048;
        #pragma unroll 4
        for (int k = 0; k < 32; ++k) {
            float4 w0 = *(const float4*)&wb[k * WROW + wphys];
            float4 w1 = *(const float4*)&wb[k * WROW + wphys + 4];
            float4 hv = *(const float4*)&hb[k * 64 + ts * 4];
            float wa[8] = {w0.x, w0.y, w0.z, w0.w, w1.x, w1.y, w1.z, w1.w};
            float ha[4] = {hv.x, hv.y, hv.z, hv.w};
            #pragma unroll
            for (int ri = 0; ri < 8; ++ri)
                #pragma unroll
                for (int si = 0; si < 4; ++si)
                    acc[ri][si] += wa[ri] * ha[si];
        }
        __syncthreads();                  // drains async loads + barrier
    }
}

// ======================= phase-1 stage bodies ==============================
__device__ __forceinline__ void emb2_body(
    int bid, int tid, float* smem, const float* __restrict__ A,
    const float* __restrict__ Wt, const float* __restrict__ bias,
    float* __restrict__ Cout)
{
    const int M = 2000;
    float* a_lds = smem;            // [32][68]
    float* b_lds = smem + 2176;     // [32][68]
    const int tn = tid & 15;
    const int th = tid >> 4;
    const int m0 = (bid & 31) * 64;
    const int j0 = (bid >> 5) * 64;

    float acc[4][4];
    #pragma unroll
    for (int x = 0; x < 4; ++x)
        #pragma unroll
        for (int y = 0; y < 4; ++y) acc[x][y] = 0.f;

    float4 abuf[2], bbuf[2];
    auto load_t = [&](int k0) {
        #pragma unroll
        for (int p = 0; p < 2; ++p) {
            int idx = tid + p * 256, ml = idx >> 3, k4 = idx & 7;
            int row = m0 + ml;
            abuf[p] = (row < M) ? *(const float4*)&A[row * 256 + k0 + k4 * 4]
                                : make_float4(0.f, 0.f, 0.f, 0.f);
            bbuf[p] = *(const float4*)&Wt[(j0 + ml) * 256 + k0 + k4 * 4];
        }
    };
    auto store_t = [&]() {
        #pragma unroll
        for (int p = 0; p < 2; ++p) {
            int idx = tid + p * 256, ml = idx >> 3, k4 = idx & 7;
            a_lds[(k4 * 4 + 0) * 68 + ml] = abuf[p].x;
            a_lds[(k4 * 4 + 1) * 68 + ml] = abuf[p].y;
            a_lds[(k4 * 4 + 2) * 68 + ml] = abuf[p].z;
            a_lds[(k4 * 4 + 3) * 68 + ml] = abuf[p].w;
            b_lds[(k4 * 4 + 0) * 68 + ml] = bbuf[p].x;
            b_lds[(k4 * 4 + 1) * 68 + ml] = bbuf[p].y;
            b_lds[(k4 * 4 + 2) * 68 + ml] = bbuf[p].z;
            b_lds[(k4 * 4 + 3) * 68 + ml] = bbuf[p].w;
        }
    };

    load_t(0); store_t(); __syncthreads();
    for (int c = 0; c < 8; ++c) {
        if (c < 7) load_t((c + 1) * 32);
        #pragma unroll 8
        for (int k = 0; k < 32; ++k) {
            float4 a4 = *(const float4*)&a_lds[k * 68 + tn * 4];
            float4 b4 = *(const float4*)&b_lds[k * 68 + th * 4];
            float av[4] = {a4.x, a4.y, a4.z, a4.w};
            float bv[4] = {b4.x, b4.y, b4.z, b4.w};
            #pragma unroll
            for (int mi = 0; mi < 4; ++mi)
                #pragma unroll
                for (int ji = 0; ji < 4; ++ji)
                    acc[mi][ji] += av[mi] * bv[ji];
        }
        __syncthreads();
        if (c < 7) { store_t(); __syncthreads(); }
    }

    const int jcol = j0 + th * 4;
    float4 bs = *(const float4*)&bias[jcol];
    #pragma unroll
    for (int mi = 0; mi < 4; ++mi) {
        int row = m0 + tn * 4 + mi;
        if (row < M) {
            float4 o;
            o.x = acc[mi][0] + bs.x;
            o.y = acc[mi][1] + bs.y;
            o.z = acc[mi][2] + bs.z;
            o.w = acc[mi][3] + bs.w;
            *(float4*)&Cout[row * 1024 + jcol] = o;
        }
    }
}

__device__ __forceinline__ void step0_body(
    int bx, int by, int tid, const int* __restrict__ tok,
    const int* __restrict__ perm, int a1, const float* __restrict__ emb2,
    float* __restrict__ cT, float* __restrict__ hT0, float* __restrict__ featsT)
{
    const int tn = tid & 15, tu = tid >> 4;
    const int u  = by * 16 + tu;
    const int n0 = bx * 64 + tn * 4;
    int4 pn = *(const int4*)&perm[n0];
    const int pns[4] = {pn.x, pn.y, pn.z, pn.w};
    float h4[4], c4[4];
    #pragma unroll
    for (int j = 0; j < 4; ++j) {
        int v = tok[pns[j] * 16];
        const float* e = emb2 + v * 1024 + u;
        float ig = e[0], gg = e[512], og = e[768];
        float c = sig_(ig) * th_(gg);
        float h = sig_(og) * th_(c);
        c4[j] = c; h4[j] = h;
        if (n0 + j >= a1) featsT[u * 4096 + pns[j]] = h;   // len == 1
    }
    *(float4*)&cT[u * 4096 + n0]  = make_float4(c4[0], c4[1], c4[2], c4[3]);
    *(float4*)&hT0[u * 4096 + n0] = make_float4(h4[0], h4[1], h4[2], h4[3]);
}

__device__ __forceinline__ void stepT_body(
    int tid, float* smem, const float* __restrict__ WT,
    const float* __restrict__ hprev, const int* __restrict__ tok, int t,
    const float* __restrict__ emb2, const int* __restrict__ perm,
    int a_t, int a_t1, int s0, int ub, float* __restrict__ cT,
    float* __restrict__ hnext, float* __restrict__ featsT, bool last)
{
    const int tr = tid & 15;
    const int ts = tid >> 4;
    const int scol = s0 + ts * 4;

    // prefetch epilogue inputs early (independent of GEMM)
    int4 pn = *(const int4*)&perm[scol];
    const int pns[4] = {pn.x, pn.y, pn.z, pn.w};
    int vids[4];
    #pragma unroll
    for (int j = 0; j < 4; ++j) vids[j] = tok[pns[j] * 16 + t];

    float acc[8][4];
    #pragma unroll
    for (int x = 0; x < 8; ++x)
        #pragma unroll
        for (int y = 0; y < 4; ++y) acc[x][y] = 0.f;

    gemm128x64_body(tid, smem, WT, ub, hprev, 4096, s0, acc);

    // epilogue: 2 units x 4 slots LSTM update
    #pragma unroll
    for (int half = 0; half < 2; ++half) {
        const int u = ub * 32 + tr * 2 + half;
        float4 cold = *(const float4*)&cT[u * 4096 + scol];
        const float* coldp = (const float*)&cold;
        float c4[4], h4[4];
        #pragma unroll
        for (int j = 0; j < 4; ++j) {
            const float* e = emb2 + vids[j] * 1024 + u;
            float ig = acc[half * 4 + 0][j] + e[0];
            float fg = acc[half * 4 + 1][j] + e[256];
            float gg = acc[half * 4 + 2][j] + e[512];
            float og = acc[half * 4 + 3][j] + e[768];
            float cc = sig_(fg) * coldp[j] + sig_(ig) * th_(gg);
            c4[j] = cc;
            h4[j] = sig_(og) * th_(cc);
            int p = scol + j;
            if (p >= a_t1 && p < a_t)      // len == t+1: last valid step
                featsT[u * 4096 + pns[j]] = h4[j];
        }
        if (!last) {                       // t==15: cT/h never read again
            *(float4*)&cT[u * 4096 + scol]    = make_float4(c4[0], c4[1], c4[2], c4[3]);
            *(float4*)&hnext[u * 4096 + scol] = make_float4(h4[0], h4[1], h4[2], h4[3]);
        }
    }
}

// ===========================================================================
// phase1 (512 blocks, regular launch + own grid barrier):
// emb2 GEMM -> step0 -> steps 1..15. Collapses 18 launches into 1.
// ===========================================================================
__global__ __launch_bounds__(256, 2)
void phase1(const float* __restrict__ emb, const float* __restrict__ tWih,
            const float* __restrict__ tb, float* __restrict__ emb2,
            const int* __restrict__ tok, const int* __restrict__ perm,
            const int* __restrict__ actcnt, const float* __restrict__ tWhhT,
            float* __restrict__ cT, float* __restrict__ hT0,
            float* __restrict__ hT1, float* __restrict__ featsT,
            unsigned* __restrict__ bar)
{
    __shared__ __align__(16) float smem[SMEMF];
    const int bid = blockIdx.x;
    const int tid = threadIdx.x;

    // ---- stage 0: emb2[v][j] = emb @ tWih^T + tb (32 x 16 tiles = 512) ----
    emb2_body(bid, tid, smem, emb, tWih, tb, emb2);
    gbar(bar, NBLK);

    // ---- stage 1: token-LSTM step 0 (1024 tiles, 2 per block) ----
    {
        const int a1 = actcnt[1];
        step0_body(bid & 63, bid >> 6, tid, tok, perm, a1, emb2, cT, hT0, featsT);
        const int i2 = bid + 512;
        step0_body(i2 & 63, i2 >> 6, tid, tok, perm, a1, emb2, cT, hT0, featsT);
    }
    gbar(bar, NBLK);

    // ---- stages 2..16: token-LSTM steps 1..15, sorted batch-parallel ----
    for (int t = 1; t < 16; ++t) {
        const float* hp = (t & 1) ? hT0 : hT1;
        float* hc       = (t & 1) ? hT1 : hT0;
        const int a_t  = actcnt[t];
        const int a_t1 = actcnt[t + 1];
        const int NT   = (((a_t + 63) >> 6) << 3);   // 8 * ceil(a_t/64)
        if (bid < NT) {
            const int ub = bid & 7;        // unit-tile constant across steps
            const int sx = bid >> 3;       // 8 neighbors share one h strip
            stepT_body(tid, smem, tWhhT, hp, tok, t, emb2, perm,
                       a_t, a_t1, sx * 64, ub, cT, hc, featsT, t == 15);
        }
        if (t < 15) gbar(bar, NBLK);       // kernel end syncs the last step
    }
}

// ======================= phase-2 stage bodies ==============================
__device__ __forceinline__ void gemmT_wrap(
    int bid, int tid, float* smem, const float* __restrict__ WT,
    const float* __restrict__ X, int xstride, const float* __restrict__ addm,
    const float* __restrict__ bias, float* __restrict__ Out)
{
    const int sx = bid & 63;
    const int rt = bid >> 6;
    const int s0 = sx * 64;
    const int tr = tid & 15;
    const int ts = tid >> 4;

    float acc[8][4];
    #pragma unroll
    for (int x = 0; x < 8; ++x)
        #pragma unroll
        for (int y = 0; y < 4; ++y) acc[x][y] = 0.f;

    gemm128x64_body(tid, smem, WT, rt, X, xstride, s0, acc);

    const int scol = s0 + ts * 4;
    #pragma unroll
    for (int ri = 0; ri < 8; ++ri) {
        const int r = rt * 128 + tr * 8 + ri;
        float4 z;
        if (addm) {
            float4 gb = *(const float4*)&addm[r * 4096 + scol];
            z.x = acc[ri][0] + gb.x; z.y = acc[ri][1] + gb.y;
            z.z = acc[ri][2] + gb.z; z.w = acc[ri][3] + gb.w;
        } else {
            float bb = bias[r];
            z.x = acc[ri][0] + bb; z.y = acc[ri][1] + bb;
            z.z = acc[ri][2] + bb; z.w = acc[ri][3] + bb;
        }
        *(float4*)&Out[r * 4096 + scol] = z;
    }
}

__device__ __forceinline__ void scan_body(
    int u, int tid, float* smem, const float* __restrict__ ZT,
    float* __restrict__ hTbuf)
{
    float* As = smem;
    float* Us = smem + 256;
    const int s0 = tid * 16;

    const float* zi = ZT + (size_t)(0 * 256 + u) * 4096 + s0;
    const float* zf = ZT + (size_t)(1 * 256 + u) * 4096 + s0;
    const float* zg = ZT + (size_t)(2 * 256 + u) * 4096 + s0;
    const float* zo = ZT + (size_t)(3 * 256 + u) * 4096 + s0;

    float4 iv[4], fv[4], gv[4], ov[4];
    #pragma unroll
    for (int p = 0; p < 4; ++p) {
        iv[p] = *(const float4*)&zi[p * 4];
        fv[p] = *(const float4*)&zf[p * 4];
        gv[p] = *(const float4*)&zg[p * 4];
        ov[p] = *(const float4*)&zo[p * 4];
    }
    float af[16], uu[16];
    const float* ivp = (const float*)iv;
    const float* fvp = (const float*)fv;
    const float* gvp = (const float*)gv;
    float A = 1.f, U = 0.f;
    #pragma unroll
    for (int k = 0; k < 16; ++k) {
        af[k] = sig_(fvp[k]);
        uu[k] = sig_(ivp[k]) * th_(gvp[k]);
        U = af[k] * U + uu[k];
        A = af[k] * A;
    }

    As[tid] = A; Us[tid] = U;
    __syncthreads();
    #pragma unroll
    for (int off = 1; off < 256; off <<= 1) {
        float eA = 1.f, eU = 0.f;
        if (tid >= off) { eA = As[tid - off]; eU = Us[tid - off]; }
        __syncthreads();
        U = A * eU + U;
        A = A * eA;
        As[tid] = A; Us[tid] = U;
        __syncthreads();
    }
    float c = (tid > 0) ? Us[tid - 1] : 0.f;  // exclusive prefix -> entry c

    float* hp = hTbuf + u * HSTRIDE + 1 + s0;
    const float* ovp = (const float*)ov;
    #pragma unroll
    for (int k = 0; k < 16; ++k) {
        c = af[k] * c + uu[k];
        hp[k] = sig_(ovp[k]) * th_(c);
    }
}

__device__ __forceinline__ void out_body(
    int tid, float* smem, const float* __restrict__ hTbuf,
    const float* __restrict__ linW, const float* __restrict__ linb,
    float* __restrict__ out)
{
    float p = hTbuf[tid * HSTRIDE + 4096] * linW[tid];
    #pragma unroll
    for (int off = 1; off < 64; off <<= 1) p += __shfl_xor(p, off);
    if ((tid & 63) == 0) smem[tid >> 6] = p;
    __syncthreads();
    if (tid == 0)
        out[0] = smem[0] + smem[1] + smem[2] + smem[3] + linb[0];
}

// ===========================================================================
// phase2 (512 blocks, regular launch + own grid barrier): feats GEMM +
// 6 scans + 5 recurrent GEMM sweeps + final linear. 13 launches -> 1.
// ===========================================================================
__global__ __launch_bounds__(256, 2)
void phase2(const float* __restrict__ iWihT, const float* __restrict__ iWhhT,
            const float* __restrict__ ib, const float* __restrict__ featsT,
            float* __restrict__ gBT, float* __restrict__ ZT,
            float* __restrict__ hTbuf, const float* __restrict__ linW,
            const float* __restrict__ linb, float* __restrict__ out,
            unsigned* __restrict__ bar)
{
    __shared__ __align__(16) float smem[SMEMF];
    const int bid = blockIdx.x;
    const int tid = threadIdx.x;

    // gBT[r][s] = ins_W_ih . featsT + ins_b
    gemmT_wrap(bid, tid, smem, iWihT, featsT, 4096, nullptr, ib, gBT);
    gbar(bar, NBLK);

    // sweep 1: h_old = 0
    if (bid < 256) scan_body(bid, tid, smem, gBT, hTbuf);
    gbar(bar, NBLK);

    for (int k = 1; k < SWEEPS; ++k) {
        gemmT_wrap(bid, tid, smem, iWhhT, hTbuf, HSTRIDE, gBT, nullptr, ZT);
        gbar(bar, NBLK);
        if (bid < 256) scan_body(bid, tid, smem, ZT, hTbuf);
        gbar(bar, NBLK);
    }

    if (bid == 0) out_body(tid, smem, hTbuf, linW, linb, out);
}

extern "C" void kernel_launch(void* const* d_in, const int* in_sizes, int n_in,
                              void* d_out, int out_size, void* d_ws, size_t ws_size,
                              hipStream_t stream)
{
    const int*   tok  = (const int*)d_in[0];
    const int*   len  = (const int*)d_in[1];
    const float* emb  = (const float*)d_in[2];
    const float* tWih = (const float*)d_in[3];
    const float* tWhh = (const float*)d_in[4];
    const float* tb   = (const float*)d_in[5];
    const float* iWih = (const float*)d_in[6];
    const float* iWhh = (const float*)d_in[7];
    const float* ib   = (const float*)d_in[8];
    const float* lW   = (const float*)d_in[9];
    const float* lb   = (const float*)d_in[10];
    float* outp = (float*)d_out;

    // workspace (floats), ~48 MB; ZT (phase 2) aliases hT0..featsT (dead)
    float* emb2   = (float*)d_ws;           // [2000][1024]   8 MB
    float* hT0    = emb2   + 2048000;       // [256][4096]    4 MB
    float* hT1    = hT0    + 1048576;       // [256][4096]
    float* cT     = hT1    + 1048576;       // [256][4096]
    float* featsT = cT     + 1048576;       // [256][4096]
    float* gBT    = featsT + 1048576;       // [1024][4096]  16 MB
    float* hTbuf  = gBT    + 4194304;       // [256][HSTRIDE], col0 = 0 pad
    float* tWhhT  = hTbuf  + 256 * HSTRIDE; // skewed W images, 1.1 MB each
    float* iWhhT  = tWhhT  + WTSZ;
    float* iWihT  = iWhhT  + WTSZ;
    int*   perm   = (int*)(iWihT + WTSZ);   // [4096]
    int*   actcnt = perm + 4096;            // [17]
    unsigned* bar = (unsigned*)(actcnt + 17); // [2] grid-barrier state
    float* ZT     = hT0;                    // [1024][4096] alias (phase 2 only)

    // setup: 3 W images + length sort + col0 zero + barrier init, concurrent
    setup_k<<<193, 256, 0, stream>>>(tWhh, iWhh, iWih, tWhhT, iWhhT, iWihT,
                                     len, perm, actcnt, hTbuf, bar);

    // phase 1: emb2 GEMM + token LSTM (grid-barriered stages)
    phase1<<<NBLK, 256, 0, stream>>>(emb, tWih, tb, emb2, tok, perm, actcnt,
                                     tWhhT, cT, hT0, hT1, featsT, bar);

    // phase 2: instruction LSTM fixed-point sweeps + output
    phase2<<<NBLK, 256, 0, stream>>>(iWihT, iWhhT, ib, featsT, gBT, ZT, hTbuf,
                                     lW, lb, outp, bar);
}

// Round 3
// 862.091 us; speedup vs baseline: 4.9277x; 4.9277x over previous
//
#include <hip/hip_runtime.h>

#define SWEEPS 6
#define HSTRIDE 4112   // hTbuf row stride: 4096 + front pad(1) + slack, %4==0
#define WROW 140       // skewed W image row: pc(rl) = rl + 4*(rl>>5), max 139
#define WTSZ (8 * 256 * WROW)   // one W image: 8 rtiles x 256 k x 140

typedef float f2 __attribute__((ext_vector_type(2)));

__device__ __forceinline__ float sig_(float x) { return 1.0f / (1.0f + __expf(-x)); }
__device__ __forceinline__ float th_(float x)  { return 1.0f - 2.0f / (__expf(2.0f * x) + 1.0f); }

// packed fp32 FMA (VOP3P, 2 FMAs/instr, full-rate on CDNA2+).
// d += a * broadcast(b.lo): both halves read src1's LOW dword (op_sel_hi[1]=0).
__device__ __forceinline__ void pk_fma_bl(f2& d, f2 a, f2 b) {
    asm("v_pk_fma_f32 %0, %1, %2, %0 op_sel_hi:[1,0,1]"
        : "+v"(d) : "v"(a), "v"(b));
}
// d += a * broadcast(b.hi): both halves read src1's HIGH dword (op_sel[1]=1).
__device__ __forceinline__ void pk_fma_bh(f2& d, f2 a, f2 b) {
    asm("v_pk_fma_f32 %0, %1, %2, %0 op_sel:[0,1,0]"
        : "+v"(d) : "v"(a), "v"(b));
}

// async global->LDS, 16B per lane. LDS dest rule: wave-uniform base + lane*16.
__device__ __forceinline__ void gload_lds16(const float* g, float* l) {
    __builtin_amdgcn_global_load_lds(
        (const __attribute__((address_space(1))) unsigned*)g,
        (__attribute__((address_space(3))) unsigned*)l, 16, 0, 0);
}

// ===========================================================================
// setup_k: blocks 0..191 = three wtrans images (64 blocks each),
//          block 192 = counting sort by length (desc) + hTbuf col0 zero.
// Replaces 4 serial launches + the 4.2 MB memset (only col 0 is ever read).
// ===========================================================================
__global__ __launch_bounds__(256)
void setup_k(const float* __restrict__ tWhh, const float* __restrict__ iWhh,
             const float* __restrict__ iWih, float* __restrict__ tWhhT,
             float* __restrict__ iWhhT, float* __restrict__ iWihT,
             const int* __restrict__ len, int* __restrict__ perm,
             int* __restrict__ actcnt, float* __restrict__ hTbuf)
{
    __shared__ __align__(16) float s[32 * WROW];
    __shared__ int cnt[17], off[17];
    const int tid = threadIdx.x;
    const int b = blockIdx.x;
    if (b < 192) {
        // WT[rt][k][pc(rl)] = W[rowmap(rt,rl)][k]; ilv=1: gate-interleaved
        const float* W; float* WT; int ilv;
        if (b < 64)       { W = tWhh; WT = tWhhT; ilv = 1; }
        else if (b < 128) { W = iWhh; WT = iWhhT; ilv = 0; }
        else              { W = iWih; WT = iWihT; ilv = 0; }
        const int bb = b & 63;
        const int k0 = (bb & 7) * 32;
        const int rt = bb >> 3;
        #pragma unroll
        for (int p = 0; p < 4; ++p) {
            int idx = tid + p * 256;
            int rl = idx >> 3, k4 = idx & 7;
            int row = ilv ? ((rl & 3) * 256 + rt * 32 + (rl >> 2))
                          : (rt * 128 + rl);
            float4 v = *(const float4*)&W[row * 256 + k0 + k4 * 4];
            int pc = rl + ((rl >> 5) << 2);
            s[(k4 * 4 + 0) * WROW + pc] = v.x;
            s[(k4 * 4 + 1) * WROW + pc] = v.y;
            s[(k4 * 4 + 2) * WROW + pc] = v.z;
            s[(k4 * 4 + 3) * WROW + pc] = v.w;
        }
        __syncthreads();
        float* dst = WT + (size_t)(rt * 256 + k0) * WROW;
        for (int i = tid; i < 32 * WROW; i += 256) dst[i] = s[i];
    } else {
        if (tid < 17) cnt[tid] = 0;
        __syncthreads();
        for (int n = tid; n < 4096; n += 256) atomicAdd(&cnt[len[n]], 1);
        __syncthreads();
        if (tid == 0) {
            int run = 0;
            for (int L = 16; L >= 1; --L) { off[L] = run; run += cnt[L]; }
            actcnt[16] = 0;
            for (int t = 1; t < 16; ++t) actcnt[t] = off[t];
            actcnt[0] = 4096;
        }
        __syncthreads();
        for (int n = tid; n < 4096; n += 256) {
            int pos = atomicAdd(&off[len[n]], 1);
            perm[pos] = n;
        }
        hTbuf[tid * HSTRIDE] = 0.f;       // h[-1] = 0
    }
}

// ===========================================================================
// emb2 build: emb2[v][j] = sum_k emb[v][k]*tWih[j][k] + tb[j]   (j = 0..1023)
// grid (32, 16), block 256, tile 64v x 64j, 4x2xf2 microtile (pk_fma).
// LDS tiles XOR-swizzled (16B granular) to break the 4-way store conflict.
// ===========================================================================
__global__ __launch_bounds__(256, 2)
void gemm_emb2(const float* __restrict__ A, const float* __restrict__ Wt,
               const float* __restrict__ bias, float* __restrict__ Cout, int M)
{
    __shared__ float a_lds[32 * 68];
    __shared__ float b_lds[32 * 68];
    const int tid = threadIdx.x;
    const int tn = tid & 15;
    const int th = tid >> 4;
    const int m0 = blockIdx.x * 64;
    const int j0 = blockIdx.y * 64;

    f2 acc2[2][4];   // [m-pair][j]; acc[mi][ji] = acc2[mi>>1][ji][mi&1]
    #pragma unroll
    for (int x = 0; x < 2; ++x)
        #pragma unroll
        for (int y = 0; y < 4; ++y) acc2[x][y] = f2{0.f, 0.f};

    // col swizzle: XOR bits 2-4 of col with bits 1-3 of row (keeps 16B groups)
    auto sw = [](int row, int col) { return col ^ (((row >> 1) & 7) << 2); };

    float4 abuf[2], bbuf[2];
    auto load_t = [&](int k0) {
        #pragma unroll
        for (int p = 0; p < 2; ++p) {
            int idx = tid + p * 256, ml = idx >> 3, k4 = idx & 7;
            int row = m0 + ml;
            abuf[p] = (row < M) ? *(const float4*)&A[row * 256 + k0 + k4 * 4]
                                : make_float4(0.f, 0.f, 0.f, 0.f);
            bbuf[p] = *(const float4*)&Wt[(j0 + ml) * 256 + k0 + k4 * 4];
        }
    };
    auto store_t = [&]() {
        #pragma unroll
        for (int p = 0; p < 2; ++p) {
            int idx = tid + p * 256, ml = idx >> 3, k4 = idx & 7;
            const float av[4] = {abuf[p].x, abuf[p].y, abuf[p].z, abuf[p].w};
            const float bv[4] = {bbuf[p].x, bbuf[p].y, bbuf[p].z, bbuf[p].w};
            #pragma unroll
            for (int c = 0; c < 4; ++c) {
                int r = k4 * 4 + c;
                a_lds[r * 68 + sw(r, ml)] = av[c];
                b_lds[r * 68 + sw(r, ml)] = bv[c];
            }
        }
    };

    load_t(0); store_t(); __syncthreads();
    for (int c = 0; c < 8; ++c) {
        if (c < 7) load_t((c + 1) * 32);
        #pragma unroll 8
        for (int k = 0; k < 32; ++k) {
            float4 a4 = *(const float4*)&a_lds[k * 68 + sw(k, tn * 4)];
            float4 b4 = *(const float4*)&b_lds[k * 68 + sw(k, th * 4)];
            f2 ap[2] = {f2{a4.x, a4.y}, f2{a4.z, a4.w}};
            f2 bp[2] = {f2{b4.x, b4.y}, f2{b4.z, b4.w}};
            #pragma unroll
            for (int mj = 0; mj < 2; ++mj) {
                pk_fma_bl(acc2[mj][0], ap[mj], bp[0]);
                pk_fma_bh(acc2[mj][1], ap[mj], bp[0]);
                pk_fma_bl(acc2[mj][2], ap[mj], bp[1]);
                pk_fma_bh(acc2[mj][3], ap[mj], bp[1]);
            }
        }
        __syncthreads();
        if (c < 7) { store_t(); __syncthreads(); }
    }

    const int jcol = j0 + th * 4;
    float4 bs = *(const float4*)&bias[jcol];
    const float bsv[4] = {bs.x, bs.y, bs.z, bs.w};
    #pragma unroll
    for (int mi = 0; mi < 4; ++mi) {
        int row = m0 + tn * 4 + mi;
        if (row < M) {
            float o[4];
            #pragma unroll
            for (int ji = 0; ji < 4; ++ji)
                o[ji] = ((mi & 1) ? acc2[mi >> 1][ji].y : acc2[mi >> 1][ji].x)
                        + bsv[ji];
            *(float4*)&Cout[row * 1024 + jcol] = make_float4(o[0], o[1], o[2], o[3]);
        }
    }
}

// ===========================================================================
// Token-LSTM step 0 (h0=c0=0 -> pointwise emb2 gather), TRANSPOSED + sorted.
// ===========================================================================
__global__ __launch_bounds__(256)
void step0T(const int* __restrict__ tok, const int* __restrict__ perm,
            const int* __restrict__ actcnt, const float* __restrict__ emb2,
            float* __restrict__ cT, float* __restrict__ hT0,
            float* __restrict__ featsT)
{
    const int tid = threadIdx.x;
    const int tn = tid & 15, tu = tid >> 4;
    const int u  = blockIdx.y * 16 + tu;
    const int n0 = blockIdx.x * 64 + tn * 4;
    const int a1 = actcnt[1];
    int4 pn = *(const int4*)&perm[n0];
    const int pns[4] = {pn.x, pn.y, pn.z, pn.w};
    float h4[4], c4[4];
    #pragma unroll
    for (int j = 0; j < 4; ++j) {
        int v = tok[pns[j] * 16];
        const float* e = emb2 + v * 1024 + u;
        float ig = e[0], gg = e[512], og = e[768];
        float c = sig_(ig) * th_(gg);
        float h = sig_(og) * th_(c);
        c4[j] = c; h4[j] = h;
        if (n0 + j >= a1) featsT[u * 4096 + pns[j]] = h;   // len == 1
    }
    *(float4*)&cT[u * 4096 + n0]  = make_float4(c4[0], c4[1], c4[2], c4[3]);
    *(float4*)&hT0[u * 4096 + n0] = make_float4(h4[0], h4[1], h4[2], h4[3]);
}

// ===========================================================================
// Shared 128r x 64s GEMM inner machinery (pk_fma version). LDS staging is
// the validated linear global_load_lds pattern; inner loop = 16 v_pk_fma_f32
// per k (w row-pairs free from b128 quads, h broadcast free via op_sel).
// acc2[rj][si]: row pc = wphys + 2*rj + elem, s = s0 + ts*4 + si.
// ===========================================================================
__device__ __forceinline__ void gemm128x64_body(
    int tid, float* wl, float* hl, const float* __restrict__ WT, int rt,
    const float* __restrict__ X, int xstride, int s0, f2 acc2[4][4])
{
    const int tr = tid & 15;
    const int ts = tid >> 4;
    const int wphys = tr * 8 + ((tr >> 2) << 2);

    auto issue_w = [&](int c, int b) {    // 1120 16B units, linear stream
        const float* src = WT + (size_t)(rt * 256 + c * 32) * WROW;
        float* dstb = wl + b * 4480;
        #pragma unroll
        for (int p = 0; p < 4; ++p) {
            int idx = tid + p * 256;
            gload_lds16(src + idx * 4, dstb + idx * 4);
        }
        if (tid < 96) {
            int idx = 1024 + tid;
            gload_lds16(src + idx * 4, dstb + idx * 4);
        }
    };
    auto issue_h = [&](int k0, int b) {
        float* dstb = hl + b * 2048;
        #pragma unroll
        for (int p = 0; p < 2; ++p) {
            int idx = tid + p * 256;
            int jj = idx >> 4, s4 = idx & 15;
            gload_lds16(&X[(size_t)(k0 + jj) * xstride + s0 + s4 * 4],
                        dstb + jj * 64 + s4 * 4);
        }
    };

    issue_w(0, 0); issue_h(0, 0); __syncthreads();
    for (int c = 0; c < 8; ++c) {
        const int b = c & 1;
        if (c < 7) { issue_w(c + 1, b ^ 1); issue_h((c + 1) * 32, b ^ 1); }
        const float* wb = wl + b * 4480;
        const float* hb = hl + b * 2048;
        #pragma unroll 4
        for (int k = 0; k < 32; ++k) {
            float4 w0 = *(const float4*)&wb[k * WROW + wphys];
            float4 w1 = *(const float4*)&wb[k * WROW + wphys + 4];
            float4 hv = *(const float4*)&hb[k * 64 + ts * 4];
            f2 wp[4] = {f2{w0.x, w0.y}, f2{w0.z, w0.w},
                        f2{w1.x, w1.y}, f2{w1.z, w1.w}};
            f2 hp[2] = {f2{hv.x, hv.y}, f2{hv.z, hv.w}};
            #pragma unroll
            for (int rj = 0; rj < 4; ++rj) {
                pk_fma_bl(acc2[rj][0], wp[rj], hp[0]);
                pk_fma_bh(acc2[rj][1], wp[rj], hp[0]);
                pk_fma_bl(acc2[rj][2], wp[rj], hp[1]);
                pk_fma_bh(acc2[rj][3], wp[rj], hp[1]);
            }
        }
        __syncthreads();                  // drains async loads + barrier
    }
}

// ===========================================================================
// Token-LSTM step t (t>=1), fused, TRANSPOSED, sorted, 128r x 64s.
// ===========================================================================
__global__ __launch_bounds__(256, 2)
void stepT(const float* __restrict__ WT, const float* __restrict__ hTprev,
           const int* __restrict__ tok, int t, const float* __restrict__ emb2,
           const int* __restrict__ perm, const int* __restrict__ actcnt,
           float* __restrict__ cT, float* __restrict__ hTnext,
           float* __restrict__ featsT)
{
    const int s0 = blockIdx.x * 64;
    const int a_t  = actcnt[t];
    if (s0 >= a_t) return;                // inactive tile: all lengths <= t
    const int a_t1 = actcnt[t + 1];

    __shared__ __align__(16) float w_lds[2 * 32 * WROW];
    __shared__ __align__(16) float h_lds[2 * 32 * 64];
    const int tid = threadIdx.x;
    const int tr = tid & 15;
    const int ts = tid >> 4;
    const int ub = blockIdx.y;            // unit-tile (32 units)
    const int scol = s0 + ts * 4;

    // prefetch epilogue inputs early (independent of GEMM)
    int4 pn = *(const int4*)&perm[scol];
    const int pns[4] = {pn.x, pn.y, pn.z, pn.w};
    int vids[4];
    #pragma unroll
    for (int j = 0; j < 4; ++j) vids[j] = tok[pns[j] * 16 + t];

    f2 acc2[4][4];
    #pragma unroll
    for (int x = 0; x < 4; ++x)
        #pragma unroll
        for (int y = 0; y < 4; ++y) acc2[x][y] = f2{0.f, 0.f};

    gemm128x64_body(tid, w_lds, h_lds, WT, ub, hTprev, 4096, s0, acc2);

    const bool last = (t == 15);          // cT/h never read after t=15
    // epilogue: 2 units x 4 slots LSTM update.
    // gate row pc = wphys + half*4 + g  ->  acc2[half*2 + (g>>1)][j][g&1]
    #pragma unroll
    for (int half = 0; half < 2; ++half) {
        const int u = ub * 32 + tr * 2 + half;
        float4 cold = *(const float4*)&cT[u * 4096 + scol];
        const float* coldp = (const float*)&cold;
        float c4[4], h4[4];
        #pragma unroll
        for (int j = 0; j < 4; ++j) {
            const float* e = emb2 + vids[j] * 1024 + u;
            float ig = acc2[half * 2 + 0][j].x + e[0];
            float fg = acc2[half * 2 + 0][j].y + e[256];
            float gg = acc2[half * 2 + 1][j].x + e[512];
            float og = acc2[half * 2 + 1][j].y + e[768];
            float cc = sig_(fg) * coldp[j] + sig_(ig) * th_(gg);
            c4[j] = cc;
            h4[j] = sig_(og) * th_(cc);
            int p = scol + j;
            if (p >= a_t1 && p < a_t)      // len == t+1: last valid step
                featsT[u * 4096 + pns[j]] = h4[j];
        }
        if (!last) {
            *(float4*)&cT[u * 4096 + scol]     = make_float4(c4[0], c4[1], c4[2], c4[3]);
            *(float4*)&hTnext[u * 4096 + scol] = make_float4(h4[0], h4[1], h4[2], h4[3]);
        }
    }
}

// ===========================================================================
// T-GEMM 128r x 64s from pre-skewed W image (linear rowmap), pk_fma inner.
// Out[r][s] = sum_k W[r][k]*X[k*xstride+s] + addm[r][s] or bias[r].
// grid (64, 8). Phase-2: X = hTbuf (HSTRIDE, front pad = s-1 shift).
// ===========================================================================
__global__ __launch_bounds__(256, 2)
void gemm_T(const float* __restrict__ WT, const float* __restrict__ X, int xstride,
            const float* __restrict__ addm, const float* __restrict__ bias,
            float* __restrict__ Out)
{
    __shared__ __align__(16) float w_lds[2 * 32 * WROW];
    __shared__ __align__(16) float h_lds[2 * 32 * 64];
    const int tid = threadIdx.x;
    const int tr = tid & 15;
    const int ts = tid >> 4;
    const int s0 = blockIdx.x * 64;
    const int rt = blockIdx.y;            // r0 = rt*128

    f2 acc2[4][4];
    #pragma unroll
    for (int x = 0; x < 4; ++x)
        #pragma unroll
        for (int y = 0; y < 4; ++y) acc2[x][y] = f2{0.f, 0.f};

    gemm128x64_body(tid, w_lds, h_lds, WT, rt, X, xstride, s0, acc2);

    const int scol = s0 + ts * 4;
    #pragma unroll
    for (int ri = 0; ri < 8; ++ri) {
        const int r = rt * 128 + tr * 8 + ri;
        float a[4];
        #pragma unroll
        for (int si = 0; si < 4; ++si)
            a[si] = (ri & 1) ? acc2[ri >> 1][si].y : acc2[ri >> 1][si].x;
        float4 z;
        if (addm) {
            float4 gb = *(const float4*)&addm[r * 4096 + scol];
            z.x = a[0] + gb.x; z.y = a[1] + gb.y;
            z.z = a[2] + gb.z; z.w = a[3] + gb.w;
        } else {
            float bb = bias[r];
            z.x = a[0] + bb; z.y = a[1] + bb;
            z.z = a[2] + bb; z.w = a[3] + bb;
        }
        *(float4*)&Out[r * 4096 + scol] = z;
    }
}

// ===========================================================================
// Sweep scan: exact per-unit affine scan of c given gate preactivations ZT,
// then h = sig(o)*tanh(c) -> hTbuf[u][1+s]. grid 256, block 256.
// ===========================================================================
__global__ __launch_bounds__(256, 1)
void scan_sweep(const float* __restrict__ ZT, float* __restrict__ hTbuf)
{
    const int u = blockIdx.x;
    const int t = threadIdx.x;
    const int s0 = t * 16;

    const float* zi = ZT + (0 * 256 + u) * 4096 + s0;
    const float* zf = ZT + (1 * 256 + u) * 4096 + s0;
    const float* zg = ZT + (2 * 256 + u) * 4096 + s0;
    const float* zo = ZT + (3 * 256 + u) * 4096 + s0;

    float4 iv[4], fv[4], gv[4], ov[4];
    #pragma unroll
    for (int p = 0; p < 4; ++p) {
        iv[p] = *(const float4*)&zi[p * 4];
        fv[p] = *(const float4*)&zf[p * 4];
        gv[p] = *(const float4*)&zg[p * 4];
        ov[p] = *(const float4*)&zo[p * 4];
    }
    float af[16], uu[16];
    const float* ivp = (const float*)iv;
    const float* fvp = (const float*)fv;
    const float* gvp = (const float*)gv;
    float A = 1.f, U = 0.f;
    #pragma unroll
    for (int k = 0; k < 16; ++k) {
        af[k] = sig_(fvp[k]);
        uu[k] = sig_(ivp[k]) * th_(gvp[k]);
        U = af[k] * U + uu[k];
        A = af[k] * A;
    }

    __shared__ float As[256], Us[256];
    As[t] = A; Us[t] = U;
    __syncthreads();
    #pragma unroll
    for (int off = 1; off < 256; off <<= 1) {
        float eA = 1.f, eU = 0.f;
        if (t >= off) { eA = As[t - off]; eU = Us[t - off]; }
        __syncthreads();
        U = A * eU + U;
        A = A * eA;
        As[t] = A; Us[t] = U;
        __syncthreads();
    }
    float c = (t > 0) ? Us[t - 1] : 0.f;  // exclusive prefix -> entry c

    float* hp = hTbuf + u * HSTRIDE + 1 + s0;
    const float* ovp = (const float*)ov;
    #pragma unroll
    for (int k = 0; k < 16; ++k) {
        c = af[k] * c + uu[k];
        hp[k] = sig_(ovp[k]) * th_(c);
    }
}

// ===========================================================================
// Final linear: out = h[4095] . lin_W + lin_b
// ===========================================================================
__global__ __launch_bounds__(256)
void out_kernel(const float* __restrict__ hTbuf, const float* __restrict__ linW,
                const float* __restrict__ linb, float* __restrict__ out)
{
    const int tid = threadIdx.x;
    __shared__ float red_lds[4];
    float p = hTbuf[tid * HSTRIDE + 4096] * linW[tid];
    #pragma unroll
    for (int off = 1; off < 64; off <<= 1) p += __shfl_xor(p, off);
    if ((tid & 63) == 0) red_lds[tid >> 6] = p;
    __syncthreads();
    if (tid == 0)
        out[0] = red_lds[0] + red_lds[1] + red_lds[2] + red_lds[3] + linb[0];
}

extern "C" void kernel_launch(void* const* d_in, const int* in_sizes, int n_in,
                              void* d_out, int out_size, void* d_ws, size_t ws_size,
                              hipStream_t stream)
{
    const int*   tok  = (const int*)d_in[0];
    const int*   len  = (const int*)d_in[1];
    const float* emb  = (const float*)d_in[2];
    const float* tWih = (const float*)d_in[3];
    const float* tWhh = (const float*)d_in[4];
    const float* tb   = (const float*)d_in[5];
    const float* iWih = (const float*)d_in[6];
    const float* iWhh = (const float*)d_in[7];
    const float* ib   = (const float*)d_in[8];
    const float* lW   = (const float*)d_in[9];
    const float* lb   = (const float*)d_in[10];
    float* out = (float*)d_out;

    // workspace (floats), ~48 MB; ZT (phase 2) aliases hT0..featsT (dead)
    float* emb2   = (float*)d_ws;           // [2000][1024]   8 MB
    float* hT0    = emb2   + 2048000;       // [256][4096]    4 MB
    float* hT1    = hT0    + 1048576;       // [256][4096]
    float* cT     = hT1    + 1048576;       // [256][4096]
    float* featsT = cT     + 1048576;       // [256][4096]
    float* gBT    = featsT + 1048576;       // [1024][4096]  16 MB
    float* hTbuf  = gBT    + 4194304;       // [256][HSTRIDE], col0 = 0 pad
    float* tWhhT  = hTbuf  + 256 * HSTRIDE; // skewed W images, 1.1 MB each
    float* iWhhT  = tWhhT  + WTSZ;
    float* iWihT  = iWhhT  + WTSZ;
    int*   perm   = (int*)(iWihT + WTSZ);   // [4096]
    int*   actcnt = perm + 4096;            // [17]
    float* ZT     = hT0;                    // [1024][4096] alias (phase 2 only)

    // setup: 3 W images + length sort + hTbuf col0 zero (replaces memset)
    setup_k<<<193, 256, 0, stream>>>(tWhh, iWhh, iWih, tWhhT, iWhhT, iWihT,
                                     len, perm, actcnt, hTbuf);

    // ---- phase 1: token LSTM, transposed, length-sorted batch-parallel ----
    gemm_emb2<<<dim3(32, 16), 256, 0, stream>>>(emb, tWih, tb, emb2, 2000);
    step0T<<<dim3(64, 16), 256, 0, stream>>>(tok, perm, actcnt, emb2, cT, hT0,
                                             featsT);
    for (int t = 1; t < 16; ++t) {
        float* hprev = (t & 1) ? hT0 : hT1;
        float* hcur  = (t & 1) ? hT1 : hT0;
        stepT<<<dim3(64, 8), 256, 0, stream>>>(tWhhT, hprev, tok, t, emb2, perm,
                                               actcnt, cT, hcur, featsT);
    }
    // gBT[r][s] = ins_W_ih . featsT + ins_b
    gemm_T<<<dim3(64, 8), 256, 0, stream>>>(iWihT, featsT, 4096, nullptr, ib, gBT);

    // ---- phase 2: fixed-point sweeps (no cross-block sync) ----
    scan_sweep<<<256, 256, 0, stream>>>(gBT, hTbuf);    // sweep 1: h_old = 0
    for (int k = 1; k < SWEEPS; ++k) {
        gemm_T<<<dim3(64, 8), 256, 0, stream>>>(iWhhT, hTbuf, HSTRIDE, gBT,
                                                nullptr, ZT);
        scan_sweep<<<256, 256, 0, stream>>>(ZT, hTbuf);
    }

    out_kernel<<<1, 256, 0, stream>>>(hTbuf, lW, lb, out);
}

// Round 4
// 853.386 us; speedup vs baseline: 4.9779x; 1.0102x over previous
//
#include <hip/hip_runtime.h>

#define SWEEPS 6
#define HSTRIDE 4112   // hTbuf row stride: 4096 + front pad(1) + slack, %4==0
#define WROW 140       // skewed W image row: pc(rl) = rl + 4*(rl>>5), max 139
#define WTSZ (8 * 256 * WROW)   // one W image: 8 rtiles x 256 k x 140

typedef float f2 __attribute__((ext_vector_type(2)));

__device__ __forceinline__ float sig_(float x) { return 1.0f / (1.0f + __expf(-x)); }
__device__ __forceinline__ float th_(float x)  { return 1.0f - 2.0f / (__expf(2.0f * x) + 1.0f); }

// packed fp32 FMA (VOP3P, 2 FMAs/instr, full-rate on CDNA2+).
// d += a * broadcast(b.lo): both halves read src1's LOW dword (op_sel_hi[1]=0).
__device__ __forceinline__ void pk_fma_bl(f2& d, f2 a, f2 b) {
    asm("v_pk_fma_f32 %0, %1, %2, %0 op_sel_hi:[1,0,1]"
        : "+v"(d) : "v"(a), "v"(b));
}
// d += a * broadcast(b.hi): both halves read src1's HIGH dword (op_sel[1]=1).
__device__ __forceinline__ void pk_fma_bh(f2& d, f2 a, f2 b) {
    asm("v_pk_fma_f32 %0, %1, %2, %0 op_sel:[0,1,0]"
        : "+v"(d) : "v"(a), "v"(b));
}

// async global->LDS, 16B per lane. LDS dest rule: wave-uniform base + lane*16.
__device__ __forceinline__ void gload_lds16(const float* g, float* l) {
    __builtin_amdgcn_global_load_lds(
        (const __attribute__((address_space(1))) unsigned*)g,
        (__attribute__((address_space(3))) unsigned*)l, 16, 0, 0);
}

// ===========================================================================
// setup_k: blocks 0..191 = three wtrans images (64 blocks each),
//          block 192 = counting sort by length (desc) + hTbuf col0 zero.
// ===========================================================================
__global__ __launch_bounds__(256)
void setup_k(const float* __restrict__ tWhh, const float* __restrict__ iWhh,
             const float* __restrict__ iWih, float* __restrict__ tWhhT,
             float* __restrict__ iWhhT, float* __restrict__ iWihT,
             const int* __restrict__ len, int* __restrict__ perm,
             int* __restrict__ actcnt, float* __restrict__ hTbuf)
{
    __shared__ __align__(16) float s[32 * WROW];
    __shared__ int cnt[17], off[17];
    const int tid = threadIdx.x;
    const int b = blockIdx.x;
    if (b < 192) {
        // WT[rt][k][pc(rl)] = W[rowmap(rt,rl)][k]; ilv=1: gate-interleaved
        const float* W; float* WT; int ilv;
        if (b < 64)       { W = tWhh; WT = tWhhT; ilv = 1; }
        else if (b < 128) { W = iWhh; WT = iWhhT; ilv = 0; }
        else              { W = iWih; WT = iWihT; ilv = 0; }
        const int bb = b & 63;
        const int k0 = (bb & 7) * 32;
        const int rt = bb >> 3;
        #pragma unroll
        for (int p = 0; p < 4; ++p) {
            int idx = tid + p * 256;
            int rl = idx >> 3, k4 = idx & 7;
            int row = ilv ? ((rl & 3) * 256 + rt * 32 + (rl >> 2))
                          : (rt * 128 + rl);
            float4 v = *(const float4*)&W[row * 256 + k0 + k4 * 4];
            int pc = rl + ((rl >> 5) << 2);
            s[(k4 * 4 + 0) * WROW + pc] = v.x;
            s[(k4 * 4 + 1) * WROW + pc] = v.y;
            s[(k4 * 4 + 2) * WROW + pc] = v.z;
            s[(k4 * 4 + 3) * WROW + pc] = v.w;
        }
        __syncthreads();
        float* dst = WT + (size_t)(rt * 256 + k0) * WROW;
        for (int i = tid; i < 32 * WROW; i += 256) dst[i] = s[i];
    } else {
        if (tid < 17) cnt[tid] = 0;
        __syncthreads();
        for (int n = tid; n < 4096; n += 256) atomicAdd(&cnt[len[n]], 1);
        __syncthreads();
        if (tid == 0) {
            int run = 0;
            for (int L = 16; L >= 1; --L) { off[L] = run; run += cnt[L]; }
            actcnt[16] = 0;
            for (int t = 1; t < 16; ++t) actcnt[t] = off[t];
            actcnt[0] = 4096;
        }
        __syncthreads();
        for (int n = tid; n < 4096; n += 256) {
            int pos = atomicAdd(&off[len[n]], 1);
            perm[pos] = n;
        }
        hTbuf[tid * HSTRIDE] = 0.f;       // h[-1] = 0
    }
}

// ===========================================================================
// emb2 build: emb2[v][j] = sum_k emb[v][k]*tWih[j][k] + tb[j]   (j = 0..1023)
// grid (32, 16), block 256, tile 64v x 64j, 4x2xf2 microtile (pk_fma).
// ===========================================================================
__global__ __launch_bounds__(256, 2)
void gemm_emb2(const float* __restrict__ A, const float* __restrict__ Wt,
               const float* __restrict__ bias, float* __restrict__ Cout, int M)
{
    __shared__ float a_lds[32 * 68];
    __shared__ float b_lds[32 * 68];
    const int tid = threadIdx.x;
    const int tn = tid & 15;
    const int th = tid >> 4;
    const int m0 = blockIdx.x * 64;
    const int j0 = blockIdx.y * 64;

    f2 acc2[2][4];   // [m-pair][j]; acc[mi][ji] = acc2[mi>>1][ji][mi&1]
    #pragma unroll
    for (int x = 0; x < 2; ++x)
        #pragma unroll
        for (int y = 0; y < 4; ++y) acc2[x][y] = f2{0.f, 0.f};

    // col swizzle: XOR bits 2-4 of col with bits 1-3 of row (keeps 16B groups)
    auto sw = [](int row, int col) { return col ^ (((row >> 1) & 7) << 2); };

    float4 abuf[2], bbuf[2];
    auto load_t = [&](int k0) {
        #pragma unroll
        for (int p = 0; p < 2; ++p) {
            int idx = tid + p * 256, ml = idx >> 3, k4 = idx & 7;
            int row = m0 + ml;
            abuf[p] = (row < M) ? *(const float4*)&A[row * 256 + k0 + k4 * 4]
                                : make_float4(0.f, 0.f, 0.f, 0.f);
            bbuf[p] = *(const float4*)&Wt[(j0 + ml) * 256 + k0 + k4 * 4];
        }
    };
    auto store_t = [&]() {
        #pragma unroll
        for (int p = 0; p < 2; ++p) {
            int idx = tid + p * 256, ml = idx >> 3, k4 = idx & 7;
            const float av[4] = {abuf[p].x, abuf[p].y, abuf[p].z, abuf[p].w};
            const float bv[4] = {bbuf[p].x, bbuf[p].y, bbuf[p].z, bbuf[p].w};
            #pragma unroll
            for (int c = 0; c < 4; ++c) {
                int r = k4 * 4 + c;
                a_lds[r * 68 + sw(r, ml)] = av[c];
                b_lds[r * 68 + sw(r, ml)] = bv[c];
            }
        }
    };

    load_t(0); store_t(); __syncthreads();
    for (int c = 0; c < 8; ++c) {
        if (c < 7) load_t((c + 1) * 32);
        #pragma unroll 8
        for (int k = 0; k < 32; ++k) {
            float4 a4 = *(const float4*)&a_lds[k * 68 + sw(k, tn * 4)];
            float4 b4 = *(const float4*)&b_lds[k * 68 + sw(k, th * 4)];
            f2 ap[2] = {f2{a4.x, a4.y}, f2{a4.z, a4.w}};
            f2 bp[2] = {f2{b4.x, b4.y}, f2{b4.z, b4.w}};
            #pragma unroll
            for (int mj = 0; mj < 2; ++mj) {
                pk_fma_bl(acc2[mj][0], ap[mj], bp[0]);
                pk_fma_bh(acc2[mj][1], ap[mj], bp[0]);
                pk_fma_bl(acc2[mj][2], ap[mj], bp[1]);
                pk_fma_bh(acc2[mj][3], ap[mj], bp[1]);
            }
        }
        __syncthreads();
        if (c < 7) { store_t(); __syncthreads(); }
    }

    const int jcol = j0 + th * 4;
    float4 bs = *(const float4*)&bias[jcol];
    const float bsv[4] = {bs.x, bs.y, bs.z, bs.w};
    #pragma unroll
    for (int mi = 0; mi < 4; ++mi) {
        int row = m0 + tn * 4 + mi;
        if (row < M) {
            float o[4];
            #pragma unroll
            for (int ji = 0; ji < 4; ++ji)
                o[ji] = ((mi & 1) ? acc2[mi >> 1][ji].y : acc2[mi >> 1][ji].x)
                        + bsv[ji];
            *(float4*)&Cout[row * 1024 + jcol] = make_float4(o[0], o[1], o[2], o[3]);
        }
    }
}

// ===========================================================================
// Token-LSTM step 0 (h0=c0=0 -> pointwise emb2 gather), TRANSPOSED + sorted.
// ===========================================================================
__global__ __launch_bounds__(256)
void step0T(const int* __restrict__ tok, const int* __restrict__ perm,
            const int* __restrict__ actcnt, const float* __restrict__ emb2,
            float* __restrict__ cT, float* __restrict__ hT0,
            float* __restrict__ featsT)
{
    const int tid = threadIdx.x;
    const int tn = tid & 15, tu = tid >> 4;
    const int u  = blockIdx.y * 16 + tu;
    const int n0 = blockIdx.x * 64 + tn * 4;
    const int a1 = actcnt[1];
    int4 pn = *(const int4*)&perm[n0];
    const int pns[4] = {pn.x, pn.y, pn.z, pn.w};
    float h4[4], c4[4];
    #pragma unroll
    for (int j = 0; j < 4; ++j) {
        int v = tok[pns[j] * 16];
        const float* e = emb2 + v * 1024 + u;
        float ig = e[0], gg = e[512], og = e[768];
        float c = sig_(ig) * th_(gg);
        float h = sig_(og) * th_(c);
        c4[j] = c; h4[j] = h;
        if (n0 + j >= a1) featsT[u * 4096 + pns[j]] = h;   // len == 1
    }
    *(float4*)&cT[u * 4096 + n0]  = make_float4(c4[0], c4[1], c4[2], c4[3]);
    *(float4*)&hT0[u * 4096 + n0] = make_float4(h4[0], h4[1], h4[2], h4[3]);
}

// ===========================================================================
// Shared 128r x 64s GEMM body, COUNTED-VMCNT pipeline (T3/T4 minimum form):
// raw s_barrier + inline s_waitcnt vmcnt(6) keeps chunk c+1's DMA loads in
// flight ACROSS the barrier (they land during compute(c)). Per-wave DMA
// counts: waves 0-1 = 7 (extra tid<96 W load), waves 2-3 = 6; vmcnt(6) is
// exact for 6-load waves, over-waits 1 load for 7-load waves (safe: FIFO).
// Buffer-overwrite hazard closed by the post-compute barrier (issue(c+2)
// only happens after it). All fences are memory-clobber asm.
// ===========================================================================
__device__ __forceinline__ void gemm128x64_body(
    int tid, float* wl, float* hl, const float* __restrict__ WT, int rt,
    const float* __restrict__ X, int xstride, int s0, f2 acc2[4][4])
{
    const int tr = tid & 15;
    const int ts = tid >> 4;
    const int wphys = tr * 8 + ((tr >> 2) << 2);

    auto issue_w = [&](int c, int b) {    // 1120 16B units, linear stream
        const float* src = WT + (size_t)(rt * 256 + c * 32) * WROW;
        float* dstb = wl + b * 4480;
        #pragma unroll
        for (int p = 0; p < 4; ++p) {
            int idx = tid + p * 256;
            gload_lds16(src + idx * 4, dstb + idx * 4);
        }
        if (tid < 96) {
            int idx = 1024 + tid;
            gload_lds16(src + idx * 4, dstb + idx * 4);
        }
    };
    auto issue_h = [&](int k0, int b) {
        float* dstb = hl + b * 2048;
        #pragma unroll
        for (int p = 0; p < 2; ++p) {
            int idx = tid + p * 256;
            int jj = idx >> 4, s4 = idx & 15;
            gload_lds16(&X[(size_t)(k0 + jj) * xstride + s0 + s4 * 4],
                        dstb + jj * 64 + s4 * 4);
        }
    };

    issue_w(0, 0); issue_h(0, 0);
    for (int c = 0; c < 8; ++c) {
        const int b = c & 1;
        if (c < 7) {
            issue_w(c + 1, b ^ 1); issue_h((c + 1) * 32, b ^ 1);
            // chunk c landed; chunk c+1 (<=7 loads) stays in flight
            asm volatile("s_waitcnt vmcnt(6)" ::: "memory");
        } else {
            asm volatile("s_waitcnt vmcnt(0)" ::: "memory");
        }
        __builtin_amdgcn_s_barrier();      // all waves' chunk c visible
        const float* wb = wl + b * 4480;
        const float* hb = hl + b * 2048;
        #pragma unroll 4
        for (int k = 0; k < 32; ++k) {
            float4 w0 = *(const float4*)&wb[k * WROW + wphys];
            float4 w1 = *(const float4*)&wb[k * WROW + wphys + 4];
            float4 hv = *(const float4*)&hb[k * 64 + ts * 4];
            f2 wp[4] = {f2{w0.x, w0.y}, f2{w0.z, w0.w},
                        f2{w1.x, w1.y}, f2{w1.z, w1.w}};
            f2 hp[2] = {f2{hv.x, hv.y}, f2{hv.z, hv.w}};
            #pragma unroll
            for (int rj = 0; rj < 4; ++rj) {
                pk_fma_bl(acc2[rj][0], wp[rj], hp[0]);
                pk_fma_bh(acc2[rj][1], wp[rj], hp[0]);
                pk_fma_bl(acc2[rj][2], wp[rj], hp[1]);
                pk_fma_bh(acc2[rj][3], wp[rj], hp[1]);
            }
        }
        asm volatile("" ::: "memory");     // pin ds_reads above the barrier
        if (c < 7) __builtin_amdgcn_s_barrier();  // buf[b] free for issue(c+2)
    }
}

// ===========================================================================
// Token-LSTM step t (t>=1), fused, TRANSPOSED, sorted, 128r x 64s.
// ===========================================================================
__global__ __launch_bounds__(256, 2)
void stepT(const float* __restrict__ WT, const float* __restrict__ hTprev,
           const int* __restrict__ tok, int t, const float* __restrict__ emb2,
           const int* __restrict__ perm, const int* __restrict__ actcnt,
           float* __restrict__ cT, float* __restrict__ hTnext,
           float* __restrict__ featsT)
{
    const int s0 = blockIdx.x * 64;
    const int a_t  = actcnt[t];
    if (s0 >= a_t) return;                // inactive tile: all lengths <= t
    const int a_t1 = actcnt[t + 1];

    __shared__ __align__(16) float w_lds[2 * 32 * WROW];
    __shared__ __align__(16) float h_lds[2 * 32 * 64];
    const int tid = threadIdx.x;
    const int tr = tid & 15;
    const int ts = tid >> 4;
    const int ub = blockIdx.y;            // unit-tile (32 units)
    const int scol = s0 + ts * 4;

    // prefetch epilogue inputs early (independent of GEMM)
    int4 pn = *(const int4*)&perm[scol];
    const int pns[4] = {pn.x, pn.y, pn.z, pn.w};
    int vids[4];
    #pragma unroll
    for (int j = 0; j < 4; ++j) vids[j] = tok[pns[j] * 16 + t];

    f2 acc2[4][4];
    #pragma unroll
    for (int x = 0; x < 4; ++x)
        #pragma unroll
        for (int y = 0; y < 4; ++y) acc2[x][y] = f2{0.f, 0.f};

    gemm128x64_body(tid, w_lds, h_lds, WT, ub, hTprev, 4096, s0, acc2);

    const bool last = (t == 15);          // cT/h never read after t=15
    // epilogue: 2 units x 4 slots LSTM update.
    // gate row pc = wphys + half*4 + g  ->  acc2[half*2 + (g>>1)][j][g&1]
    #pragma unroll
    for (int half = 0; half < 2; ++half) {
        const int u = ub * 32 + tr * 2 + half;
        float4 cold = *(const float4*)&cT[u * 4096 + scol];
        const float* coldp = (const float*)&cold;
        float c4[4], h4[4];
        #pragma unroll
        for (int j = 0; j < 4; ++j) {
            const float* e = emb2 + vids[j] * 1024 + u;
            float ig = acc2[half * 2 + 0][j].x + e[0];
            float fg = acc2[half * 2 + 0][j].y + e[256];
            float gg = acc2[half * 2 + 1][j].x + e[512];
            float og = acc2[half * 2 + 1][j].y + e[768];
            float cc = sig_(fg) * coldp[j] + sig_(ig) * th_(gg);
            c4[j] = cc;
            h4[j] = sig_(og) * th_(cc);
            int p = scol + j;
            if (p >= a_t1 && p < a_t)      // len == t+1: last valid step
                featsT[u * 4096 + pns[j]] = h4[j];
        }
        if (!last) {
            *(float4*)&cT[u * 4096 + scol]     = make_float4(c4[0], c4[1], c4[2], c4[3]);
            *(float4*)&hTnext[u * 4096 + scol] = make_float4(h4[0], h4[1], h4[2], h4[3]);
        }
    }
}

// ===========================================================================
// T-GEMM 128r x 64s from pre-skewed W image (linear rowmap), pk_fma inner.
// Out[r][s] = sum_k W[r][k]*X[k*xstride+s] + addm[r][s] or bias[r].
// grid (64, 8). Phase-2: X = hTbuf (HSTRIDE, front pad = s-1 shift).
// ===========================================================================
__global__ __launch_bounds__(256, 2)
void gemm_T(const float* __restrict__ WT, const float* __restrict__ X, int xstride,
            const float* __restrict__ addm, const float* __restrict__ bias,
            float* __restrict__ Out)
{
    __shared__ __align__(16) float w_lds[2 * 32 * WROW];
    __shared__ __align__(16) float h_lds[2 * 32 * 64];
    const int tid = threadIdx.x;
    const int tr = tid & 15;
    const int ts = tid >> 4;
    const int s0 = blockIdx.x * 64;
    const int rt = blockIdx.y;            // r0 = rt*128

    f2 acc2[4][4];
    #pragma unroll
    for (int x = 0; x < 4; ++x)
        #pragma unroll
        for (int y = 0; y < 4; ++y) acc2[x][y] = f2{0.f, 0.f};

    gemm128x64_body(tid, w_lds, h_lds, WT, rt, X, xstride, s0, acc2);

    const int scol = s0 + ts * 4;
    #pragma unroll
    for (int ri = 0; ri < 8; ++ri) {
        const int r = rt * 128 + tr * 8 + ri;
        float a[4];
        #pragma unroll
        for (int si = 0; si < 4; ++si)
            a[si] = (ri & 1) ? acc2[ri >> 1][si].y : acc2[ri >> 1][si].x;
        float4 z;
        if (addm) {
            float4 gb = *(const float4*)&addm[r * 4096 + scol];
            z.x = a[0] + gb.x; z.y = a[1] + gb.y;
            z.z = a[2] + gb.z; z.w = a[3] + gb.w;
        } else {
            float bb = bias[r];
            z.x = a[0] + bb; z.y = a[1] + bb;
            z.z = a[2] + bb; z.w = a[3] + bb;
        }
        *(float4*)&Out[r * 4096 + scol] = z;
    }
}

// ===========================================================================
// Sweep scan: exact per-unit affine scan of c given gate preactivations ZT,
// then h = sig(o)*tanh(c) -> hTbuf[u][1+s]. grid 256, block 256.
// Wave-level shfl_up scan (in-register) + 1-barrier cross-wave fold
// replaces the 16-barrier LDS doubling network.
// ===========================================================================
__global__ __launch_bounds__(256, 1)
void scan_sweep(const float* __restrict__ ZT, float* __restrict__ hTbuf)
{
    const int u = blockIdx.x;
    const int t = threadIdx.x;
    const int s0 = t * 16;

    const float* zi = ZT + (0 * 256 + u) * 4096 + s0;
    const float* zf = ZT + (1 * 256 + u) * 4096 + s0;
    const float* zg = ZT + (2 * 256 + u) * 4096 + s0;
    const float* zo = ZT + (3 * 256 + u) * 4096 + s0;

    float4 iv[4], fv[4], gv[4], ov[4];
    #pragma unroll
    for (int p = 0; p < 4; ++p) {
        iv[p] = *(const float4*)&zi[p * 4];
        fv[p] = *(const float4*)&zf[p * 4];
        gv[p] = *(const float4*)&zg[p * 4];
        ov[p] = *(const float4*)&zo[p * 4];
    }
    float af[16], uu[16];
    const float* ivp = (const float*)iv;
    const float* fvp = (const float*)fv;
    const float* gvp = (const float*)gv;
    float A = 1.f, U = 0.f;
    #pragma unroll
    for (int k = 0; k < 16; ++k) {
        af[k] = sig_(fvp[k]);
        uu[k] = sig_(ivp[k]) * th_(gvp[k]);
        U = af[k] * U + uu[k];
        A = af[k] * A;
    }

    // wave-level inclusive scan over lanes (lane asc = time asc);
    // compose cur∘prev: U = A_cur*U_prev + U_cur, A = A_cur*A_prev
    const int lane = t & 63;
    #pragma unroll
    for (int off = 1; off < 64; off <<= 1) {
        float pA = __shfl_up(A, off);
        float pU = __shfl_up(U, off);
        if (lane >= off) { U = A * pU + U; A = A * pA; }
    }
    // exclusive-within-wave prefix
    float lexA = __shfl_up(A, 1);
    float lexU = __shfl_up(U, 1);
    if (lane == 0) { lexA = 1.f; lexU = 0.f; }

    __shared__ float sA[4], sU[4];
    const int w = t >> 6;
    if (lane == 63) { sA[w] = A; sU[w] = U; }
    __syncthreads();
    float eU = 0.f;                       // waves 0..w-1 applied to c0=0
    #pragma unroll
    for (int i = 0; i < 3; ++i)
        if (i < w) eU = sA[i] * eU + sU[i];

    float c = lexA * eU + lexU;           // exclusive prefix -> entry c

    float* hp = hTbuf + u * HSTRIDE + 1 + s0;
    const float* ovp = (const float*)ov;
    #pragma unroll
    for (int k = 0; k < 16; ++k) {
        c = af[k] * c + uu[k];
        hp[k] = sig_(ovp[k]) * th_(c);
    }
}

// ===========================================================================
// Final linear: out = h[4095] . lin_W + lin_b
// ===========================================================================
__global__ __launch_bounds__(256)
void out_kernel(const float* __restrict__ hTbuf, const float* __restrict__ linW,
                const float* __restrict__ linb, float* __restrict__ out)
{
    const int tid = threadIdx.x;
    __shared__ float red_lds[4];
    float p = hTbuf[tid * HSTRIDE + 4096] * linW[tid];
    #pragma unroll
    for (int off = 1; off < 64; off <<= 1) p += __shfl_xor(p, off);
    if ((tid & 63) == 0) red_lds[tid >> 6] = p;
    __syncthreads();
    if (tid == 0)
        out[0] = red_lds[0] + red_lds[1] + red_lds[2] + red_lds[3] + linb[0];
}

extern "C" void kernel_launch(void* const* d_in, const int* in_sizes, int n_in,
                              void* d_out, int out_size, void* d_ws, size_t ws_size,
                              hipStream_t stream)
{
    const int*   tok  = (const int*)d_in[0];
    const int*   len  = (const int*)d_in[1];
    const float* emb  = (const float*)d_in[2];
    const float* tWih = (const float*)d_in[3];
    const float* tWhh = (const float*)d_in[4];
    const float* tb   = (const float*)d_in[5];
    const float* iWih = (const float*)d_in[6];
    const float* iWhh = (const float*)d_in[7];
    const float* ib   = (const float*)d_in[8];
    const float* lW   = (const float*)d_in[9];
    const float* lb   = (const float*)d_in[10];
    float* out = (float*)d_out;

    // workspace (floats), ~48 MB; ZT (phase 2) aliases hT0..featsT (dead)
    float* emb2   = (float*)d_ws;           // [2000][1024]   8 MB
    float* hT0    = emb2   + 2048000;       // [256][4096]    4 MB
    float* hT1    = hT0    + 1048576;       // [256][4096]
    float* cT     = hT1    + 1048576;       // [256][4096]
    float* featsT = cT     + 1048576;       // [256][4096]
    float* gBT    = featsT + 1048576;       // [1024][4096]  16 MB
    float* hTbuf  = gBT    + 4194304;       // [256][HSTRIDE], col0 = 0 pad
    float* tWhhT  = hTbuf  + 256 * HSTRIDE; // skewed W images, 1.1 MB each
    float* iWhhT  = tWhhT  + WTSZ;
    float* iWihT  = iWhhT  + WTSZ;
    int*   perm   = (int*)(iWihT + WTSZ);   // [4096]
    int*   actcnt = perm + 4096;            // [17]
    float* ZT     = hT0;                    // [1024][4096] alias (phase 2 only)

    // setup: 3 W images + length sort + hTbuf col0 zero (replaces memset)
    setup_k<<<193, 256, 0, stream>>>(tWhh, iWhh, iWih, tWhhT, iWhhT, iWihT,
                                     len, perm, actcnt, hTbuf);

    // ---- phase 1: token LSTM, transposed, length-sorted batch-parallel ----
    gemm_emb2<<<dim3(32, 16), 256, 0, stream>>>(emb, tWih, tb, emb2, 2000);
    step0T<<<dim3(64, 16), 256, 0, stream>>>(tok, perm, actcnt, emb2, cT, hT0,
                                             featsT);
    for (int t = 1; t < 16; ++t) {
        float* hprev = (t & 1) ? hT0 : hT1;
        float* hcur  = (t & 1) ? hT1 : hT0;
        stepT<<<dim3(64, 8), 256, 0, stream>>>(tWhhT, hprev, tok, t, emb2, perm,
                                               actcnt, cT, hcur, featsT);
    }
    // gBT[r][s] = ins_W_ih . featsT + ins_b
    gemm_T<<<dim3(64, 8), 256, 0, stream>>>(iWihT, featsT, 4096, nullptr, ib, gBT);

    // ---- phase 2: fixed-point sweeps (no cross-block sync) ----
    scan_sweep<<<256, 256, 0, stream>>>(gBT, hTbuf);    // sweep 1: h_old = 0
    for (int k = 1; k < SWEEPS; ++k) {
        gemm_T<<<dim3(64, 8), 256, 0, stream>>>(iWhhT, hTbuf, HSTRIDE, gBT,
                                                nullptr, ZT);
        scan_sweep<<<256, 256, 0, stream>>>(ZT, hTbuf);
    }

    out_kernel<<<1, 256, 0, stream>>>(hTbuf, lW, lb, out);
}